// Round 8
// baseline (124.997 us; speedup 1.0000x reference)
//
#include <hip/hip_runtime.h>
#include <hip/hip_bf16.h>

#define D_IN 1386
#define EPS 1e-5f
#define CHUNKS 44            // ceil(1386/32)
#define KHALF 22

typedef __attribute__((ext_vector_type(8))) short short8v;
typedef __attribute__((ext_vector_type(4))) float f32x4;
typedef unsigned short ushortt;

__device__ inline unsigned short bf16rne(float f) {
    unsigned int u = __float_as_uint(f);
    u += 0x7FFFu + ((u >> 16) & 1u);
    return (unsigned short)(u >> 16);
}
__device__ inline float bfbits_to_f(unsigned short b) {
    return __uint_as_float(((unsigned int)b) << 16);
}

union S8U { short8v s; unsigned int u[4]; };

// packed pair f32->bf16 (RNE, v_cvt_pk_bf16_f32) + residuals
__device__ inline unsigned int cvt2(float v0, float v1, float& r0, float& r1) {
    union { __hip_bfloat162 b2; unsigned int u; } cv;
    cv.b2 = __float22bfloat162_rn(make_float2(v0, v1));
    r0 = v0 - __uint_as_float((cv.u & 0xFFFFu) << 16);
    r1 = v1 - __uint_as_float(cv.u & 0xFFFF0000u);
    return cv.u;
}
__device__ inline unsigned int cvt2n(float v0, float v1) {
    union { __hip_bfloat162 b2; unsigned int u; } cv;
    cv.b2 = __float22bfloat162_rn(make_float2(v0, v1));
    return cv.u;
}

// ---------------- Kernel 0: precompute triple-split W1 in frag-image order --
// short index: c*6144 + (3T+s)*512 + l*8 + j -> split_s( w[16T+(l&15)][32c+8*(l>>4)+j] )
__global__ __launch_bounds__(256) void prep_w3(const float* __restrict__ w,
                                               ushortt* __restrict__ w3) {
    int idx = blockIdx.x * 256 + threadIdx.x;
    if (idx >= CHUNKS * 6144) return;
    int c   = idx / 6144;
    int rem = idx - c * 6144;
    int g   = rem >> 9;
    int l   = (rem >> 3) & 63;
    int j   = rem & 7;
    int T   = g / 3, s = g - 3 * T;
    int h   = 16 * T + (l & 15);
    int k   = 32 * c + 8 * (l >> 4) + j;
    float v = (k < D_IN) ? w[h * D_IN + k] : 0.f;
    unsigned short hh = bf16rne(v);
    float r1 = v - bfbits_to_f(hh);
    unsigned short mm = bf16rne(r1);
    float r2 = r1 - bfbits_to_f(mm);
    unsigned short ll = bf16rne(r2);
    w3[idx] = (s == 0) ? hh : (s == 1) ? mm : ll;
}

// ---------------- Kernel 1: y_part[kh] = x @ fc1_w.T (K-half kh) ------------
// Grid 1024 = 512 sample-blocks (M=32) x 2 K-halves (22 chunks). Block =
// 256 thr = 4 waves, one per h-tile T. Per chunk, the block stages into a
// double-buffered LDS image: B = 12KB w3 chunk (coalesced dwordx4 -> b128
// writes) and A = 6KB of x split to bf16-triple ONCE per element (coalesced
// 128B/row global loads). One barrier/chunk. Waves read fragments with
// ds_read_b128 (A frags same addr across waves -> broadcast). 4 blocks/CU.
__global__ __launch_bounds__(256, 4) void fc1_mfma(const float* __restrict__ x,
                                                   const ushortt* __restrict__ w3,
                                                   float* __restrict__ ypart) {
    __shared__ ushortt lds[2][9216];   // [buf]: shorts [0,6144)=B, [6144,9216)=A
    const int t    = threadIdx.x;
    const int lane = t & 63;
    const int T    = t >> 6;           // wave id = h-tile
    const int kh   = blockIdx.x & 1;
    const int sb   = blockIdx.x >> 1;
    const int n0   = sb * 32;
    const int c0   = kh * KHALF;
    const int r    = lane & 15;
    const int g4   = lane >> 4;
    // staging role: row/unit for x
    const int row  = t >> 3;           // 0..31
    const int u    = t & 7;            // k-quad within chunk
    const int sgw  = row >> 4;
    const int lanew = (row & 15) + 16 * (u >> 1);
    const int half = u & 1;
    const float* xp0 = x + (size_t)(n0 + row) * D_IN + 4 * u;

    f32x4 acc[2];
    acc[0] = (f32x4){0.f, 0.f, 0.f, 0.f};
    acc[1] = (f32x4){0.f, 0.f, 0.f, 0.f};

    uint4 bB[3];
    float xf[4];

    auto stage_load = [&](int c) {
        const ushortt* wp = w3 + (size_t)c * 6144 + t * 8;
        bB[0] = *(const uint4*)(wp);
        bB[1] = *(const uint4*)(wp + 2048);
        bB[2] = *(const uint4*)(wp + 4096);
        const float* xp = xp0 + 32 * c;
        if (c < CHUNKS - 1) {
            float2 v0 = *(const float2*)xp;
            float2 v1 = *(const float2*)(xp + 2);
            xf[0] = v0.x; xf[1] = v0.y; xf[2] = v1.x; xf[3] = v1.y;
        } else {
            const int k0 = 32 * c + 4 * u;
#pragma unroll
            for (int e = 0; e < 4; ++e)
                xf[e] = (k0 + e < D_IN) ? xp[e] : 0.f;
        }
    };
    auto stage_write = [&](int nb) {
#pragma unroll
        for (int i = 0; i < 3; ++i)
            *(uint4*)&lds[nb][i * 2048 + t * 8] = bB[i];
        float m0, m1, m2, m3, l0, l1, l2, l3;
        unsigned int h01 = cvt2(xf[0], xf[1], m0, m1);
        unsigned int h23 = cvt2(xf[2], xf[3], m2, m3);
        unsigned int q01 = cvt2(m0, m1, l0, l1);
        unsigned int q23 = cvt2(m2, m3, l2, l3);
        unsigned int w01 = cvt2n(l0, l1);
        unsigned int w23 = cvt2n(l2, l3);
        ushortt* ab = &lds[nb][6144 + sgw * 1536 + lanew * 8 + half * 4];
        *(uint2*)(ab)         = make_uint2(h01, h23);
        *(uint2*)(ab + 512)   = make_uint2(q01, q23);
        *(uint2*)(ab + 1024)  = make_uint2(w01, w23);
    };
    auto compute = [&](int cb) {
        const ushortt* base = &lds[cb][0];
        const short8v Bh = *(const short8v*)(base + (3 * T + 0) * 512 + lane * 8);
        const short8v Bm = *(const short8v*)(base + (3 * T + 1) * 512 + lane * 8);
        const short8v Bl = *(const short8v*)(base + (3 * T + 2) * 512 + lane * 8);
#pragma unroll
        for (int sg = 0; sg < 2; ++sg) {
            const ushortt* ab = base + 6144 + sg * 1536 + lane * 8;
            const short8v XH = *(const short8v*)(ab);
            const short8v XM = *(const short8v*)(ab + 512);
            const short8v XL = *(const short8v*)(ab + 1024);
            f32x4 c = acc[sg];
            c = __builtin_amdgcn_mfma_f32_16x16x32_bf16(XL, Bh, c, 0, 0, 0);
            c = __builtin_amdgcn_mfma_f32_16x16x32_bf16(XM, Bm, c, 0, 0, 0);
            c = __builtin_amdgcn_mfma_f32_16x16x32_bf16(XH, Bl, c, 0, 0, 0);
            c = __builtin_amdgcn_mfma_f32_16x16x32_bf16(XM, Bh, c, 0, 0, 0);
            c = __builtin_amdgcn_mfma_f32_16x16x32_bf16(XH, Bm, c, 0, 0, 0);
            c = __builtin_amdgcn_mfma_f32_16x16x32_bf16(XH, Bh, c, 0, 0, 0);
            acc[sg] = c;
        }
    };

    // prologue
    stage_load(c0);
    stage_write(0);
    __syncthreads();

    for (int i = 0; i < KHALF; ++i) {
        const int cb = i & 1;
        if (i + 1 < KHALF) stage_load(c0 + i + 1);   // issue early (regs)
        compute(cb);
        if (i + 1 < KHALF) stage_write(cb ^ 1);      // waits loads, fills other buf
        __syncthreads();
    }

    // D layout: row(sample) = sg*16 + 4*g4+q, col(h) = 16T + r
    float* yp = ypart + (size_t)kh * (16384 * 64);
#pragma unroll
    for (int sg = 0; sg < 2; ++sg)
#pragma unroll
        for (int q = 0; q < 4; ++q)
            yp[(size_t)(n0 + sg * 16 + 4 * g4 + q) * 64 + 16 * T + r] = acc[sg][q];
}

// ---------------- Kernel 2: 64-step LIF recurrence, h'-split 4 ways ---------
// Block = 4 waves x 16 samples; wave T owns h' in [16T,16T+16). All LIF state
// lane-local in D layout. Spikes exchanged per step via double-buffered LDS.
// Reads the two K-half partials of fc1 and sums them (free K-reduction).
__global__ __launch_bounds__(256, 4) void snn_kernel(
    const float* __restrict__ y,
    const float* __restrict__ fc1_b,
    const float* __restrict__ bn1_g, const float* __restrict__ bn1_b,
    const float* __restrict__ bn1_m, const float* __restrict__ bn1_v,
    const float* __restrict__ fc2_w, const float* __restrict__ fc2_b,
    const float* __restrict__ bn2_g, const float* __restrict__ bn2_b,
    const float* __restrict__ bn2_m, const float* __restrict__ bn2_v,
    const float* __restrict__ cls_w, const float* __restrict__ cls_b,
    float* __restrict__ out)
{
    __shared__ unsigned int spk[2][16][36];
    __shared__ float redc[4][16][4];
    const int lane = threadIdx.x & 63;
    const int T    = threadIdx.x >> 6;
    const int n0   = blockIdx.x * 16;
    const int r    = lane & 15;
    const int grp  = lane >> 4;

    short8v Whi[2], Wlo[2];
    {
        const int hp = 16 * T + r;
        const float scale = bn2_g[hp] / sqrtf(bn2_v[hp] + EPS);
#pragma unroll
        for (int Hh = 0; Hh < 2; ++Hh) {
            S8U hi, lo;
#pragma unroll
            for (int d = 0; d < 4; ++d) {
                const int kk = 32 * Hh + 8 * grp + 2 * d;
                float w0 = fc2_w[hp * 64 + kk]     * scale;
                float w1 = fc2_w[hp * 64 + kk + 1] * scale;
                unsigned short h0 = bf16rne(w0), h1 = bf16rne(w1);
                unsigned short l0 = bf16rne(w0 - bfbits_to_f(h0));
                unsigned short l1 = bf16rne(w1 - bfbits_to_f(h1));
                hi.u[d] = (unsigned int)h0 | ((unsigned int)h1 << 16);
                lo.u[d] = (unsigned int)l0 | ((unsigned int)l1 << 16);
            }
            Whi[Hh] = hi.s;
            Wlo[Hh] = lo.s;
        }
    }

    const int h0 = 16 * T + 4 * grp;
    float a1[4], biasD[4];
    {
        float4 ya = *(const float4*)&y[(size_t)(n0 + r) * 64 + h0];
        float4 yb = *(const float4*)&y[(size_t)16384 * 64 + (size_t)(n0 + r) * 64 + h0];
#pragma unroll
        for (int q = 0; q < 4; ++q) {
            const int h = h0 + q;
            float s1v = bn1_g[h] / sqrtf(bn1_v[h] + EPS);
            float yq  = (q == 0) ? ya.x + yb.x : (q == 1) ? ya.y + yb.y
                      : (q == 2) ? ya.z + yb.z : ya.w + yb.w;
            a1[q] = (yq + fc1_b[h] - bn1_m[h]) * s1v + bn1_b[h];
            const float s2v = bn2_g[h] / sqrtf(bn2_v[h] + EPS);
            biasD[q] = (fc2_b[h] - bn2_m[h]) * s2v + bn2_b[h];
        }
    }

    float v1[4], v2[4], cnt[4];
#pragma unroll
    for (int q = 0; q < 4; ++q) { v1[q] = 0.f; v2[q] = 0.f; cnt[q] = 0.f; }

    for (int t = 0; t < 64; ++t) {
        const int b = t & 1;
        unsigned int dw0, dw1;
        {
            float h1a = v1[0] + (a1[0] - v1[0]) * 0.5f;
            float h1b = v1[1] + (a1[1] - v1[1]) * 0.5f;
            float h1c = v1[2] + (a1[2] - v1[2]) * 0.5f;
            float h1d = v1[3] + (a1[3] - v1[3]) * 0.5f;
            bool sa = h1a >= 1.f, sb = h1b >= 1.f, sc = h1c >= 1.f, sd = h1d >= 1.f;
            v1[0] = sa ? 0.f : h1a; v1[1] = sb ? 0.f : h1b;
            v1[2] = sc ? 0.f : h1c; v1[3] = sd ? 0.f : h1d;
            dw0 = (sa ? 0x3F80u : 0u) | (sb ? 0x3F800000u : 0u);
            dw1 = (sc ? 0x3F80u : 0u) | (sd ? 0x3F800000u : 0u);
        }
        *(uint2*)&spk[b][r][8 * T + 2 * grp] = make_uint2(dw0, dw1);
        __syncthreads();
        uint4 wv0 = *(const uint4*)&spk[b][r][4 * grp];
        uint4 wv1 = *(const uint4*)&spk[b][r][16 + 4 * grp];
        S8U s0u, s1u;
        s0u.u[0] = wv0.x; s0u.u[1] = wv0.y; s0u.u[2] = wv0.z; s0u.u[3] = wv0.w;
        s1u.u[0] = wv1.x; s1u.u[1] = wv1.y; s1u.u[2] = wv1.z; s1u.u[3] = wv1.w;
        const short8v S0 = s0u.s, S1 = s1u.s;

        f32x4 c1;
        c1[0] = biasD[0]; c1[1] = biasD[1]; c1[2] = biasD[2]; c1[3] = biasD[3];
        f32x4 c2 = (f32x4){0.f, 0.f, 0.f, 0.f};
        c1 = __builtin_amdgcn_mfma_f32_16x16x32_bf16(Whi[0], S0, c1, 0, 0, 0);
        c2 = __builtin_amdgcn_mfma_f32_16x16x32_bf16(Wlo[0], S0, c2, 0, 0, 0);
        c1 = __builtin_amdgcn_mfma_f32_16x16x32_bf16(Whi[1], S1, c1, 0, 0, 0);
        c2 = __builtin_amdgcn_mfma_f32_16x16x32_bf16(Wlo[1], S1, c2, 0, 0, 0);

#pragma unroll
        for (int q = 0; q < 4; ++q) {
            float z  = c1[q] + c2[q];
            float h2 = v2[q] + (z - v2[q]) * 0.5f;
            bool s = h2 >= 1.f;
            v2[q] = s ? 0.f : h2;
            cnt[q] += s ? 1.f : 0.f;
        }
    }

    float p[4];
#pragma unroll
    for (int c = 0; c < 4; ++c) {
        p[c] = cnt[0] * cls_w[c * 64 + h0]     + cnt[1] * cls_w[c * 64 + h0 + 1]
             + cnt[2] * cls_w[c * 64 + h0 + 2] + cnt[3] * cls_w[c * 64 + h0 + 3];
        p[c] += __shfl_xor(p[c], 16);
        p[c] += __shfl_xor(p[c], 32);
    }
    if (lane < 16) {
        float4 v; v.x = p[0]; v.y = p[1]; v.z = p[2]; v.w = p[3];
        *(float4*)&redc[T][lane][0] = v;
    }
    __syncthreads();
    if (threadIdx.x < 16) {
        const int s = threadIdx.x;
        float4 o;
        o.x = (redc[0][s][0] + redc[1][s][0] + redc[2][s][0] + redc[3][s][0]) * (1.f / 64.f) + cls_b[0];
        o.y = (redc[0][s][1] + redc[1][s][1] + redc[2][s][1] + redc[3][s][1]) * (1.f / 64.f) + cls_b[1];
        o.z = (redc[0][s][2] + redc[1][s][2] + redc[2][s][2] + redc[3][s][2]) * (1.f / 64.f) + cls_b[2];
        o.w = (redc[0][s][3] + redc[1][s][3] + redc[2][s][3] + redc[3][s][3]) * (1.f / 64.f) + cls_b[3];
        *(float4*)&out[(size_t)(n0 + s) * 4] = o;
    }
}

extern "C" void kernel_launch(void* const* d_in, const int* in_sizes, int n_in,
                              void* d_out, int out_size, void* d_ws, size_t ws_size,
                              hipStream_t stream) {
    const float* x     = (const float*)d_in[0];
    const float* fc1_w = (const float*)d_in[1];
    const float* fc1_b = (const float*)d_in[2];
    const float* bn1_g = (const float*)d_in[3];
    const float* bn1_b = (const float*)d_in[4];
    const float* bn1_m = (const float*)d_in[5];
    const float* bn1_v = (const float*)d_in[6];
    const float* fc2_w = (const float*)d_in[7];
    const float* fc2_b = (const float*)d_in[8];
    const float* bn2_g = (const float*)d_in[9];
    const float* bn2_b = (const float*)d_in[10];
    const float* bn2_m = (const float*)d_in[11];
    const float* bn2_v = (const float*)d_in[12];
    const float* cls_w = (const float*)d_in[13];
    const float* cls_b = (const float*)d_in[14];

    float*   ypart = (float*)d_ws;                          // 2 x 4 MB
    ushortt* w3    = (ushortt*)((char*)d_ws + (8 << 20));   // 528 KB

    prep_w3 <<<1056, 256, 0, stream>>>(fc1_w, w3);
    fc1_mfma<<<1024, 256, 0, stream>>>(x, w3, ypart);
    snn_kernel<<<1024, 256, 0, stream>>>(ypart, fc1_b, bn1_g, bn1_b, bn1_m, bn1_v,
                                         fc2_w, fc2_b, bn2_g, bn2_b, bn2_m, bn2_v,
                                         cls_w, cls_b, (float*)d_out);
}

// Round 10
// 91.755 us; speedup vs baseline: 1.3623x; 1.3623x over previous
//
#include <hip/hip_runtime.h>
#include <hip/hip_bf16.h>

#define D_IN 1386
#define EPS 1e-5f
#define CHUNKS 44            // ceil(1386/32); last chunk has 10 valid floats

typedef __attribute__((ext_vector_type(8))) short short8v;
typedef __attribute__((ext_vector_type(4))) float f32x4;
typedef unsigned short ushortt;

__device__ inline unsigned short bf16rne(float f) {
    unsigned int u = __float_as_uint(f);
    u += 0x7FFFu + ((u >> 16) & 1u);
    return (unsigned short)(u >> 16);
}
__device__ inline float bfbits_to_f(unsigned short b) {
    return __uint_as_float(((unsigned int)b) << 16);
}

union S8U { short8v s; unsigned int u[4]; };

// packed pair f32->bf16 (RNE, v_cvt_pk_bf16_f32) + residuals
__device__ inline unsigned int cvt2(float v0, float v1, float& r0, float& r1) {
    union { __hip_bfloat162 b2; unsigned int u; } cv;
    cv.b2 = __float22bfloat162_rn(make_float2(v0, v1));
    r0 = v0 - __uint_as_float((cv.u & 0xFFFFu) << 16);
    r1 = v1 - __uint_as_float(cv.u & 0xFFFF0000u);
    return cv.u;
}
__device__ inline unsigned int cvt2n(float v0, float v1) {
    union { __hip_bfloat162 b2; unsigned int u; } cv;
    cv.b2 = __float22bfloat162_rn(make_float2(v0, v1));
    return cv.u;
}

// ---------------- Kernel 0: precompute triple-split W1 in frag-image order --
// short index: c*6144 + (3T+s)*512 + l*8 + j -> split_s( w[16T+(l&15)][32c+8*(l>>4)+j] )
__global__ __launch_bounds__(256) void prep_w3(const float* __restrict__ w,
                                               ushortt* __restrict__ w3) {
    int idx = blockIdx.x * 256 + threadIdx.x;
    if (idx >= CHUNKS * 6144) return;
    int c   = idx / 6144;
    int rem = idx - c * 6144;
    int g   = rem >> 9;
    int l   = (rem >> 3) & 63;
    int j   = rem & 7;
    int T   = g / 3, s = g - 3 * T;
    int h   = 16 * T + (l & 15);
    int k   = 32 * c + 8 * (l >> 4) + j;
    float v = (k < D_IN) ? w[h * D_IN + k] : 0.f;
    unsigned short hh = bf16rne(v);
    float r1 = v - bfbits_to_f(hh);
    unsigned short mm = bf16rne(r1);
    float r2 = r1 - bfbits_to_f(mm);
    unsigned short ll = bf16rne(r2);
    w3[idx] = (s == 0) ? hh : (s == 1) ? mm : ll;
}

// ---------------- Kernel 1: y = x @ fc1_w.T --------------------------------
// Grid 512 x 512thr: block = 8 waves = 2 sample-groups (sg) x 4 h-tiles (T).
// Wave = 16 samples x 16 h x full K. 2 blocks/CU -> 16 waves/CU = 4/SIMD.
// DEEP static register pipeline: A-ring depth 6, B-ring depth 3, chunk loop
// fully unrolled so every ring index is compile-time. ORDER: body(c) consumes
// its slot FIRST, then chunk c+D is issued into the freed slot (R8 bug was
// the reverse -> clobbered the slot before consumption). Issue->use distance
// = D bodies (~700 cyc for A) -> HBM latency covered; residual stalls overlap
// across 4 waves/SIMD. No LDS, no barriers.
__global__ __launch_bounds__(512, 4) void fc1_mfma(const float* __restrict__ x,
                                                   const ushortt* __restrict__ w3,
                                                   float* __restrict__ y) {
    const int lane = threadIdx.x & 63;
    const int wid  = threadIdx.x >> 6;
    const int T    = wid & 3;            // h-tile
    const int sg   = wid >> 2;           // sample group
    const int n0   = blockIdx.x * 32 + sg * 16;
    const int r    = lane & 15;
    const int g4   = lane >> 4;
    const float* xrow = x + (size_t)(n0 + r) * D_IN + 8 * g4;
    const ushortt* wT = w3 + 3 * T * 512;

    f32x4 acc = (f32x4){0.f, 0.f, 0.f, 0.f};

    float   a[6][8];     // A ring (depth 6): lane's 8 floats per chunk
    short8v B[3][3];     // B ring (depth 3): 3 frag-groups per chunk

    auto issueA = [&](int c, int s) {
        if (c < CHUNKS - 1) {
            const float2* p = (const float2*)(xrow + 32 * c);
            float2 v0 = p[0], v1 = p[1], v2 = p[2], v3 = p[3];
            a[s][0] = v0.x; a[s][1] = v0.y; a[s][2] = v1.x; a[s][3] = v1.y;
            a[s][4] = v2.x; a[s][5] = v2.y; a[s][6] = v3.x; a[s][7] = v3.y;
        } else {
            const float* p = xrow + 32 * (CHUNKS - 1);
#pragma unroll
            for (int j = 0; j < 8; ++j) {
                int kk = 8 * g4 + j;           // +1376 = global k
                a[s][j] = (kk < D_IN - 32 * (CHUNKS - 1)) ? p[j] : 0.f;
            }
        }
    };
    auto issueB = [&](int c, int s) {
        const short8v* bp = (const short8v*)(wT + (size_t)c * 6144) + lane;
        B[s][0] = bp[0];
        B[s][1] = bp[64];
        B[s][2] = bp[128];
    };
    auto body = [&](int sa, int sb) {
        S8U Ah, Am, Al;
#pragma unroll
        for (int d = 0; d < 4; ++d) {
            float m0, m1, l0, l1;
            Ah.u[d] = cvt2(a[sa][2 * d], a[sa][2 * d + 1], m0, m1);
            Am.u[d] = cvt2(m0, m1, l0, l1);
            Al.u[d] = cvt2n(l0, l1);
        }
        const short8v XH = Ah.s, XM = Am.s, XL = Al.s;
        const short8v Bh = B[sb][0], Bm = B[sb][1], Bl = B[sb][2];
        acc = __builtin_amdgcn_mfma_f32_16x16x32_bf16(XL, Bh, acc, 0, 0, 0);
        acc = __builtin_amdgcn_mfma_f32_16x16x32_bf16(XM, Bm, acc, 0, 0, 0);
        acc = __builtin_amdgcn_mfma_f32_16x16x32_bf16(XH, Bl, acc, 0, 0, 0);
        acc = __builtin_amdgcn_mfma_f32_16x16x32_bf16(XM, Bh, acc, 0, 0, 0);
        acc = __builtin_amdgcn_mfma_f32_16x16x32_bf16(XH, Bm, acc, 0, 0, 0);
        acc = __builtin_amdgcn_mfma_f32_16x16x32_bf16(XH, Bh, acc, 0, 0, 0);
    };

    // prologue: fill rings (chunks 0..5 for A, 0..2 for B)
#pragma unroll
    for (int c = 0; c < 6; ++c) issueA(c, c);
#pragma unroll
    for (int c = 0; c < 3; ++c) issueB(c, c);

    // fully unrolled steady state: consume c FIRST, then refill freed slots
#pragma unroll
    for (int c = 0; c < CHUNKS; ++c) {
        body(c % 6, c % 3);
        if (c + 6 < CHUNKS) issueA(c + 6, c % 6);
        if (c + 3 < CHUNKS) issueB(c + 3, c % 3);
    }

    // D layout: row (sample) = 4*g4+q, col (h) = 16T + r
#pragma unroll
    for (int q = 0; q < 4; ++q)
        y[(size_t)(n0 + 4 * g4 + q) * 64 + 16 * T + r] = acc[q];
}

// ---------------- Kernel 2: 64-step LIF recurrence, h'-split 4 ways ---------
// (R6 version, verified.) Block = 4 waves x 16 samples; wave T owns h' in
// [16T,16T+16); LIF state lane-local in D layout; spikes exchanged per step
// via double-buffered LDS. Grid 1024 -> 4 waves/SIMD.
__global__ __launch_bounds__(256, 4) void snn_kernel(
    const float* __restrict__ y,
    const float* __restrict__ fc1_b,
    const float* __restrict__ bn1_g, const float* __restrict__ bn1_b,
    const float* __restrict__ bn1_m, const float* __restrict__ bn1_v,
    const float* __restrict__ fc2_w, const float* __restrict__ fc2_b,
    const float* __restrict__ bn2_g, const float* __restrict__ bn2_b,
    const float* __restrict__ bn2_m, const float* __restrict__ bn2_v,
    const float* __restrict__ cls_w, const float* __restrict__ cls_b,
    float* __restrict__ out)
{
    __shared__ unsigned int spk[2][16][36];
    __shared__ float redc[4][16][4];
    const int lane = threadIdx.x & 63;
    const int T    = threadIdx.x >> 6;
    const int n0   = blockIdx.x * 16;
    const int r    = lane & 15;
    const int grp  = lane >> 4;

    short8v Whi[2], Wlo[2];
    {
        const int hp = 16 * T + r;
        const float scale = bn2_g[hp] / sqrtf(bn2_v[hp] + EPS);
#pragma unroll
        for (int Hh = 0; Hh < 2; ++Hh) {
            S8U hi, lo;
#pragma unroll
            for (int d = 0; d < 4; ++d) {
                const int kk = 32 * Hh + 8 * grp + 2 * d;
                float w0 = fc2_w[hp * 64 + kk]     * scale;
                float w1 = fc2_w[hp * 64 + kk + 1] * scale;
                unsigned short h0 = bf16rne(w0), h1 = bf16rne(w1);
                unsigned short l0 = bf16rne(w0 - bfbits_to_f(h0));
                unsigned short l1 = bf16rne(w1 - bfbits_to_f(h1));
                hi.u[d] = (unsigned int)h0 | ((unsigned int)h1 << 16);
                lo.u[d] = (unsigned int)l0 | ((unsigned int)l1 << 16);
            }
            Whi[Hh] = hi.s;
            Wlo[Hh] = lo.s;
        }
    }

    const int h0 = 16 * T + 4 * grp;
    float a1[4], biasD[4];
    {
        float4 yv = *(const float4*)&y[(size_t)(n0 + r) * 64 + h0];
#pragma unroll
        for (int q = 0; q < 4; ++q) {
            const int h = h0 + q;
            float s1v = bn1_g[h] / sqrtf(bn1_v[h] + EPS);
            float yq  = (q == 0) ? yv.x : (q == 1) ? yv.y : (q == 2) ? yv.z : yv.w;
            a1[q] = (yq + fc1_b[h] - bn1_m[h]) * s1v + bn1_b[h];
            const float s2v = bn2_g[h] / sqrtf(bn2_v[h] + EPS);
            biasD[q] = (fc2_b[h] - bn2_m[h]) * s2v + bn2_b[h];
        }
    }

    float v1[4], v2[4], cnt[4];
#pragma unroll
    for (int q = 0; q < 4; ++q) { v1[q] = 0.f; v2[q] = 0.f; cnt[q] = 0.f; }

    for (int t = 0; t < 64; ++t) {
        const int b = t & 1;
        unsigned int dw0, dw1;
        {
            float h1a = v1[0] + (a1[0] - v1[0]) * 0.5f;
            float h1b = v1[1] + (a1[1] - v1[1]) * 0.5f;
            float h1c = v1[2] + (a1[2] - v1[2]) * 0.5f;
            float h1d = v1[3] + (a1[3] - v1[3]) * 0.5f;
            bool sa = h1a >= 1.f, sb = h1b >= 1.f, sc = h1c >= 1.f, sd = h1d >= 1.f;
            v1[0] = sa ? 0.f : h1a; v1[1] = sb ? 0.f : h1b;
            v1[2] = sc ? 0.f : h1c; v1[3] = sd ? 0.f : h1d;
            dw0 = (sa ? 0x3F80u : 0u) | (sb ? 0x3F800000u : 0u);
            dw1 = (sc ? 0x3F80u : 0u) | (sd ? 0x3F800000u : 0u);
        }
        *(uint2*)&spk[b][r][8 * T + 2 * grp] = make_uint2(dw0, dw1);
        __syncthreads();
        uint4 wv0 = *(const uint4*)&spk[b][r][4 * grp];
        uint4 wv1 = *(const uint4*)&spk[b][r][16 + 4 * grp];
        S8U s0u, s1u;
        s0u.u[0] = wv0.x; s0u.u[1] = wv0.y; s0u.u[2] = wv0.z; s0u.u[3] = wv0.w;
        s1u.u[0] = wv1.x; s1u.u[1] = wv1.y; s1u.u[2] = wv1.z; s1u.u[3] = wv1.w;
        const short8v S0 = s0u.s, S1 = s1u.s;

        f32x4 c1;
        c1[0] = biasD[0]; c1[1] = biasD[1]; c1[2] = biasD[2]; c1[3] = biasD[3];
        f32x4 c2 = (f32x4){0.f, 0.f, 0.f, 0.f};
        c1 = __builtin_amdgcn_mfma_f32_16x16x32_bf16(Whi[0], S0, c1, 0, 0, 0);
        c2 = __builtin_amdgcn_mfma_f32_16x16x32_bf16(Wlo[0], S0, c2, 0, 0, 0);
        c1 = __builtin_amdgcn_mfma_f32_16x16x32_bf16(Whi[1], S1, c1, 0, 0, 0);
        c2 = __builtin_amdgcn_mfma_f32_16x16x32_bf16(Wlo[1], S1, c2, 0, 0, 0);

#pragma unroll
        for (int q = 0; q < 4; ++q) {
            float z  = c1[q] + c2[q];
            float h2 = v2[q] + (z - v2[q]) * 0.5f;
            bool s = h2 >= 1.f;
            v2[q] = s ? 0.f : h2;
            cnt[q] += s ? 1.f : 0.f;
        }
    }

    float p[4];
#pragma unroll
    for (int c = 0; c < 4; ++c) {
        p[c] = cnt[0] * cls_w[c * 64 + h0]     + cnt[1] * cls_w[c * 64 + h0 + 1]
             + cnt[2] * cls_w[c * 64 + h0 + 2] + cnt[3] * cls_w[c * 64 + h0 + 3];
        p[c] += __shfl_xor(p[c], 16);
        p[c] += __shfl_xor(p[c], 32);
    }
    if (lane < 16) {
        float4 v; v.x = p[0]; v.y = p[1]; v.z = p[2]; v.w = p[3];
        *(float4*)&redc[T][lane][0] = v;
    }
    __syncthreads();
    if (threadIdx.x < 16) {
        const int s = threadIdx.x;
        float4 o;
        o.x = (redc[0][s][0] + redc[1][s][0] + redc[2][s][0] + redc[3][s][0]) * (1.f / 64.f) + cls_b[0];
        o.y = (redc[0][s][1] + redc[1][s][1] + redc[2][s][1] + redc[3][s][1]) * (1.f / 64.f) + cls_b[1];
        o.z = (redc[0][s][2] + redc[1][s][2] + redc[2][s][2] + redc[3][s][2]) * (1.f / 64.f) + cls_b[2];
        o.w = (redc[0][s][3] + redc[1][s][3] + redc[2][s][3] + redc[3][s][3]) * (1.f / 64.f) + cls_b[3];
        *(float4*)&out[(size_t)(n0 + s) * 4] = o;
    }
}

extern "C" void kernel_launch(void* const* d_in, const int* in_sizes, int n_in,
                              void* d_out, int out_size, void* d_ws, size_t ws_size,
                              hipStream_t stream) {
    const float* x     = (const float*)d_in[0];
    const float* fc1_w = (const float*)d_in[1];
    const float* fc1_b = (const float*)d_in[2];
    const float* bn1_g = (const float*)d_in[3];
    const float* bn1_b = (const float*)d_in[4];
    const float* bn1_m = (const float*)d_in[5];
    const float* bn1_v = (const float*)d_in[6];
    const float* fc2_w = (const float*)d_in[7];
    const float* fc2_b = (const float*)d_in[8];
    const float* bn2_g = (const float*)d_in[9];
    const float* bn2_b = (const float*)d_in[10];
    const float* bn2_m = (const float*)d_in[11];
    const float* bn2_v = (const float*)d_in[12];
    const float* cls_w = (const float*)d_in[13];
    const float* cls_b = (const float*)d_in[14];

    float*   y  = (float*)d_ws;                            // 4 MB
    ushortt* w3 = (ushortt*)((char*)d_ws + (4 << 20));     // 528 KB

    prep_w3 <<<1056, 256, 0, stream>>>(fc1_w, w3);
    fc1_mfma<<<512,  512, 0, stream>>>(x, w3, y);
    snn_kernel<<<1024, 256, 0, stream>>>(y, fc1_b, bn1_g, bn1_b, bn1_m, bn1_v,
                                         fc2_w, fc2_b, bn2_g, bn2_b, bn2_m, bn2_v,
                                         cls_w, cls_b, (float*)d_out);
}

// Round 11
// 75.323 us; speedup vs baseline: 1.6595x; 1.2181x over previous
//
#include <hip/hip_runtime.h>
#include <hip/hip_bf16.h>

#define D_IN 1386
#define EPS 1e-5f
#define CHUNKS 44            // ceil(1386/32); last chunk has 10 valid floats

typedef __attribute__((ext_vector_type(8))) short short8v;
typedef __attribute__((ext_vector_type(4))) float f32x4;
typedef unsigned short ushortt;

__device__ inline unsigned short bf16rne(float f) {
    unsigned int u = __float_as_uint(f);
    u += 0x7FFFu + ((u >> 16) & 1u);
    return (unsigned short)(u >> 16);
}
__device__ inline float bfbits_to_f(unsigned short b) {
    return __uint_as_float(((unsigned int)b) << 16);
}

union S8U { short8v s; unsigned int u[4]; };

// packed pair f32->bf16 (RNE, v_cvt_pk_bf16_f32) + residuals
__device__ inline unsigned int cvt2(float v0, float v1, float& r0, float& r1) {
    union { __hip_bfloat162 b2; unsigned int u; } cv;
    cv.b2 = __float22bfloat162_rn(make_float2(v0, v1));
    r0 = v0 - __uint_as_float((cv.u & 0xFFFFu) << 16);
    r1 = v1 - __uint_as_float(cv.u & 0xFFFF0000u);
    return cv.u;
}
__device__ inline unsigned int cvt2n(float v0, float v1) {
    union { __hip_bfloat162 b2; unsigned int u; } cv;
    cv.b2 = __float22bfloat162_rn(make_float2(v0, v1));
    return cv.u;
}

// ---------------- Kernel 0: precompute triple-split W1 in frag-image order --
// short index: c*6144 + (3T+s)*512 + l*8 + j -> split_s( w[16T+(l&15)][32c+8*(l>>4)+j] )
__global__ __launch_bounds__(256) void prep_w3(const float* __restrict__ w,
                                               ushortt* __restrict__ w3) {
    int idx = blockIdx.x * 256 + threadIdx.x;
    if (idx >= CHUNKS * 6144) return;
    int c   = idx / 6144;
    int rem = idx - c * 6144;
    int g   = rem >> 9;
    int l   = (rem >> 3) & 63;
    int j   = rem & 7;
    int T   = g / 3, s = g - 3 * T;
    int h   = 16 * T + (l & 15);
    int k   = 32 * c + 8 * (l >> 4) + j;
    float v = (k < D_IN) ? w[h * D_IN + k] : 0.f;
    unsigned short hh = bf16rne(v);
    float r1 = v - bfbits_to_f(hh);
    unsigned short mm = bf16rne(r1);
    float r2 = r1 - bfbits_to_f(mm);
    unsigned short ll = bf16rne(r2);
    w3[idx] = (s == 0) ? hh : (s == 1) ? mm : ll;
}

// ---------------- Kernel 1: y = x @ fc1_w.T --------------------------------
// snn-style barrier-paced pipeline. Block = 16 samples, 4 waves (wave T owns
// h-tile T). Grid 1024 -> 4 blocks/CU = 4 waves/SIMD. Per chunk: each thread
// loads one float2 of x(c+2) (coalesced, 128B/row), triple-splits ONCE, writes
// 3 x b32 to double-buffered LDS [3][16][40] (80B row stride); waves read A
// frags via 3 x ds_read_b128 (conflict-free), B from depth-2 register ring
// (L1-resident w3). ONE barrier/chunk = the scheduling fence the compiler
// cannot sink loads across.
__global__ __launch_bounds__(256, 4) void fc1_mfma(const float* __restrict__ x,
                                                   const ushortt* __restrict__ w3,
                                                   float* __restrict__ y) {
    __shared__ ushortt asp[2][3][16][40];   // 7.7 KB: [buf][split][sample][k(+pad)]
    const int t    = threadIdx.x;
    const int lane = t & 63;
    const int T    = t >> 6;           // wave id = h-tile
    const int n0   = blockIdx.x * 16;
    const int r    = lane & 15;
    const int g4   = lane >> 4;
    // staging role: thread -> (sample row, float-pair)
    const int srow = t >> 4;           // 0..15
    const int kp   = t & 15;           // 0..15 -> k-pair 2*kp
    const float* xs = x + (size_t)(n0 + srow) * D_IN + 2 * kp;

    f32x4 acc = (f32x4){0.f, 0.f, 0.f, 0.f};
    short8v Br[2][3];                  // B ring, depth 2
    float fA0, fA1, fB0, fB1;          // x staging pairs (parity A=even chunk)

    auto stage_load = [&](int c, bool pa) {
        float v0 = 0.f, v1 = 0.f;
        if (c < CHUNKS - 1) {
            float2 v = *(const float2*)(xs + 32 * c);
            v0 = v.x; v1 = v.y;
        } else {
            int k0 = 32 * c + 2 * kp;
            if (k0 < D_IN)     v0 = xs[32 * c];
            if (k0 + 1 < D_IN) v1 = xs[32 * c + 1];
        }
        if (pa) { fA0 = v0; fA1 = v1; } else { fB0 = v0; fB1 = v1; }
    };
    auto stage_write = [&](int nb, bool pa) {
        float u0 = pa ? fA0 : fB0, u1 = pa ? fA1 : fB1;
        float m0, m1, l0, l1;
        unsigned int hi = cvt2(u0, u1, m0, m1);
        unsigned int mi = cvt2(m0, m1, l0, l1);
        unsigned int lo = cvt2n(l0, l1);
        *(unsigned int*)&asp[nb][0][srow][2 * kp] = hi;
        *(unsigned int*)&asp[nb][1][srow][2 * kp] = mi;
        *(unsigned int*)&asp[nb][2][srow][2 * kp] = lo;
    };
    auto issueB = [&](int c, int s) {
        const short8v* bp = (const short8v*)(w3 + (size_t)c * 6144 + 3 * T * 512) + lane;
        Br[s][0] = bp[0];
        Br[s][1] = bp[64];
        Br[s][2] = bp[128];
    };
    auto compute = [&](int cb, int sb) {
        const short8v XH = *(const short8v*)&asp[cb][0][r][8 * g4];
        const short8v XM = *(const short8v*)&asp[cb][1][r][8 * g4];
        const short8v XL = *(const short8v*)&asp[cb][2][r][8 * g4];
        const short8v Bh = Br[sb][0], Bm = Br[sb][1], Bl = Br[sb][2];
        acc = __builtin_amdgcn_mfma_f32_16x16x32_bf16(XL, Bh, acc, 0, 0, 0);
        acc = __builtin_amdgcn_mfma_f32_16x16x32_bf16(XM, Bm, acc, 0, 0, 0);
        acc = __builtin_amdgcn_mfma_f32_16x16x32_bf16(XH, Bl, acc, 0, 0, 0);
        acc = __builtin_amdgcn_mfma_f32_16x16x32_bf16(XM, Bh, acc, 0, 0, 0);
        acc = __builtin_amdgcn_mfma_f32_16x16x32_bf16(XH, Bm, acc, 0, 0, 0);
        acc = __builtin_amdgcn_mfma_f32_16x16x32_bf16(XH, Bh, acc, 0, 0, 0);
    };

    // prologue: chunk0 staged to buf0; chunk1 pair loaded; B ring filled
    stage_load(0, true);
    stage_write(0, true);
    stage_load(1, false);
    issueB(0, 0);
    issueB(1, 1);
    __syncthreads();

#pragma unroll
    for (int c = 0; c < CHUNKS; ++c) {
        const int cb = c & 1;
        const bool pa = (cb == 0);     // parity of chunk c
        compute(cb, cb);
        // load x for chunk c+2 into the pair freed this iteration (parity cb)
        if (c + 2 < CHUNKS) stage_load(c + 2, pa);
        // refill B ring slot cb with chunk c+2 (consumed this iteration)
        if (c + 2 < CHUNKS) issueB(c + 2, cb);
        // write chunk c+1 (held in the OTHER pair) into the other LDS buffer
        if (c + 1 < CHUNKS) stage_write(cb ^ 1, !pa);
        __syncthreads();
    }

    // D layout: row (sample-local) = 4*g4+q, col (h-local) = r
#pragma unroll
    for (int q = 0; q < 4; ++q)
        y[(size_t)(n0 + 4 * g4 + q) * 64 + 16 * T + r] = acc[q];
}

// ---------------- Kernel 2: 64-step LIF recurrence, h'-split 4 ways ---------
// (R6 version, verified.)
__global__ __launch_bounds__(256, 4) void snn_kernel(
    const float* __restrict__ y,
    const float* __restrict__ fc1_b,
    const float* __restrict__ bn1_g, const float* __restrict__ bn1_b,
    const float* __restrict__ bn1_m, const float* __restrict__ bn1_v,
    const float* __restrict__ fc2_w, const float* __restrict__ fc2_b,
    const float* __restrict__ bn2_g, const float* __restrict__ bn2_b,
    const float* __restrict__ bn2_m, const float* __restrict__ bn2_v,
    const float* __restrict__ cls_w, const float* __restrict__ cls_b,
    float* __restrict__ out)
{
    __shared__ unsigned int spk[2][16][36];
    __shared__ float redc[4][16][4];
    const int lane = threadIdx.x & 63;
    const int T    = threadIdx.x >> 6;
    const int n0   = blockIdx.x * 16;
    const int r    = lane & 15;
    const int grp  = lane >> 4;

    short8v Whi[2], Wlo[2];
    {
        const int hp = 16 * T + r;
        const float scale = bn2_g[hp] / sqrtf(bn2_v[hp] + EPS);
#pragma unroll
        for (int Hh = 0; Hh < 2; ++Hh) {
            S8U hi, lo;
#pragma unroll
            for (int d = 0; d < 4; ++d) {
                const int kk = 32 * Hh + 8 * grp + 2 * d;
                float w0 = fc2_w[hp * 64 + kk]     * scale;
                float w1 = fc2_w[hp * 64 + kk + 1] * scale;
                unsigned short h0 = bf16rne(w0), h1 = bf16rne(w1);
                unsigned short l0 = bf16rne(w0 - bfbits_to_f(h0));
                unsigned short l1 = bf16rne(w1 - bfbits_to_f(h1));
                hi.u[d] = (unsigned int)h0 | ((unsigned int)h1 << 16);
                lo.u[d] = (unsigned int)l0 | ((unsigned int)l1 << 16);
            }
            Whi[Hh] = hi.s;
            Wlo[Hh] = lo.s;
        }
    }

    const int h0 = 16 * T + 4 * grp;
    float a1[4], biasD[4];
    {
        float4 yv = *(const float4*)&y[(size_t)(n0 + r) * 64 + h0];
#pragma unroll
        for (int q = 0; q < 4; ++q) {
            const int h = h0 + q;
            float s1v = bn1_g[h] / sqrtf(bn1_v[h] + EPS);
            float yq  = (q == 0) ? yv.x : (q == 1) ? yv.y : (q == 2) ? yv.z : yv.w;
            a1[q] = (yq + fc1_b[h] - bn1_m[h]) * s1v + bn1_b[h];
            const float s2v = bn2_g[h] / sqrtf(bn2_v[h] + EPS);
            biasD[q] = (fc2_b[h] - bn2_m[h]) * s2v + bn2_b[h];
        }
    }

    float v1[4], v2[4], cnt[4];
#pragma unroll
    for (int q = 0; q < 4; ++q) { v1[q] = 0.f; v2[q] = 0.f; cnt[q] = 0.f; }

    for (int t = 0; t < 64; ++t) {
        const int b = t & 1;
        unsigned int dw0, dw1;
        {
            float h1a = v1[0] + (a1[0] - v1[0]) * 0.5f;
            float h1b = v1[1] + (a1[1] - v1[1]) * 0.5f;
            float h1c = v1[2] + (a1[2] - v1[2]) * 0.5f;
            float h1d = v1[3] + (a1[3] - v1[3]) * 0.5f;
            bool sa = h1a >= 1.f, sb = h1b >= 1.f, sc = h1c >= 1.f, sd = h1d >= 1.f;
            v1[0] = sa ? 0.f : h1a; v1[1] = sb ? 0.f : h1b;
            v1[2] = sc ? 0.f : h1c; v1[3] = sd ? 0.f : h1d;
            dw0 = (sa ? 0x3F80u : 0u) | (sb ? 0x3F800000u : 0u);
            dw1 = (sc ? 0x3F80u : 0u) | (sd ? 0x3F800000u : 0u);
        }
        *(uint2*)&spk[b][r][8 * T + 2 * grp] = make_uint2(dw0, dw1);
        __syncthreads();
        uint4 wv0 = *(const uint4*)&spk[b][r][4 * grp];
        uint4 wv1 = *(const uint4*)&spk[b][r][16 + 4 * grp];
        S8U s0u, s1u;
        s0u.u[0] = wv0.x; s0u.u[1] = wv0.y; s0u.u[2] = wv0.z; s0u.u[3] = wv0.w;
        s1u.u[0] = wv1.x; s1u.u[1] = wv1.y; s1u.u[2] = wv1.z; s1u.u[3] = wv1.w;
        const short8v S0 = s0u.s, S1 = s1u.s;

        f32x4 c1;
        c1[0] = biasD[0]; c1[1] = biasD[1]; c1[2] = biasD[2]; c1[3] = biasD[3];
        f32x4 c2 = (f32x4){0.f, 0.f, 0.f, 0.f};
        c1 = __builtin_amdgcn_mfma_f32_16x16x32_bf16(Whi[0], S0, c1, 0, 0, 0);
        c2 = __builtin_amdgcn_mfma_f32_16x16x32_bf16(Wlo[0], S0, c2, 0, 0, 0);
        c1 = __builtin_amdgcn_mfma_f32_16x16x32_bf16(Whi[1], S1, c1, 0, 0, 0);
        c2 = __builtin_amdgcn_mfma_f32_16x16x32_bf16(Wlo[1], S1, c2, 0, 0, 0);

#pragma unroll
        for (int q = 0; q < 4; ++q) {
            float z  = c1[q] + c2[q];
            float h2 = v2[q] + (z - v2[q]) * 0.5f;
            bool s = h2 >= 1.f;
            v2[q] = s ? 0.f : h2;
            cnt[q] += s ? 1.f : 0.f;
        }
    }

    float p[4];
#pragma unroll
    for (int c = 0; c < 4; ++c) {
        p[c] = cnt[0] * cls_w[c * 64 + h0]     + cnt[1] * cls_w[c * 64 + h0 + 1]
             + cnt[2] * cls_w[c * 64 + h0 + 2] + cnt[3] * cls_w[c * 64 + h0 + 3];
        p[c] += __shfl_xor(p[c], 16);
        p[c] += __shfl_xor(p[c], 32);
    }
    if (lane < 16) {
        float4 v; v.x = p[0]; v.y = p[1]; v.z = p[2]; v.w = p[3];
        *(float4*)&redc[T][lane][0] = v;
    }
    __syncthreads();
    if (threadIdx.x < 16) {
        const int s = threadIdx.x;
        float4 o;
        o.x = (redc[0][s][0] + redc[1][s][0] + redc[2][s][0] + redc[3][s][0]) * (1.f / 64.f) + cls_b[0];
        o.y = (redc[0][s][1] + redc[1][s][1] + redc[2][s][1] + redc[3][s][1]) * (1.f / 64.f) + cls_b[1];
        o.z = (redc[0][s][2] + redc[1][s][2] + redc[2][s][2] + redc[3][s][2]) * (1.f / 64.f) + cls_b[2];
        o.w = (redc[0][s][3] + redc[1][s][3] + redc[2][s][3] + redc[3][s][3]) * (1.f / 64.f) + cls_b[3];
        *(float4*)&out[(size_t)(n0 + s) * 4] = o;
    }
}

extern "C" void kernel_launch(void* const* d_in, const int* in_sizes, int n_in,
                              void* d_out, int out_size, void* d_ws, size_t ws_size,
                              hipStream_t stream) {
    const float* x     = (const float*)d_in[0];
    const float* fc1_w = (const float*)d_in[1];
    const float* fc1_b = (const float*)d_in[2];
    const float* bn1_g = (const float*)d_in[3];
    const float* bn1_b = (const float*)d_in[4];
    const float* bn1_m = (const float*)d_in[5];
    const float* bn1_v = (const float*)d_in[6];
    const float* fc2_w = (const float*)d_in[7];
    const float* fc2_b = (const float*)d_in[8];
    const float* bn2_g = (const float*)d_in[9];
    const float* bn2_b = (const float*)d_in[10];
    const float* bn2_m = (const float*)d_in[11];
    const float* bn2_v = (const float*)d_in[12];
    const float* cls_w = (const float*)d_in[13];
    const float* cls_b = (const float*)d_in[14];

    float*   y  = (float*)d_ws;                            // 4 MB
    ushortt* w3 = (ushortt*)((char*)d_ws + (4 << 20));     // 528 KB

    prep_w3 <<<1056, 256, 0, stream>>>(fc1_w, w3);
    fc1_mfma<<<1024, 256, 0, stream>>>(x, w3, y);
    snn_kernel<<<1024, 256, 0, stream>>>(y, fc1_b, bn1_g, bn1_b, bn1_m, bn1_v,
                                         fc2_w, fc2_b, bn2_g, bn2_b, bn2_m, bn2_v,
                                         cls_w, cls_b, (float*)d_out);
}